// Round 1
// baseline (249.203 us; speedup 1.0000x reference)
//
#include <hip/hip_runtime.h>

typedef unsigned short u16;
typedef unsigned int u32;
typedef __attribute__((ext_vector_type(8))) short bf16x8;
typedef __attribute__((ext_vector_type(4))) float f32x4;

__device__ __forceinline__ u16 f2bf(float f) {
    u32 u = __builtin_bit_cast(u32, f);
    u += 0x7FFFu + ((u >> 16) & 1u);
    return (u16)(u >> 16);
}
__device__ __forceinline__ float bf2f(u16 s) {
    u32 u = ((u32)s) << 16;
    return __builtin_bit_cast(float, u);
}
__device__ __forceinline__ float sigm(float x) {
    return 1.0f / (1.0f + __expf(-x));
}

// ---------------- P1: x (B,C,H,W) fp32 -> x' [p][c] bf16, p=(b*64+h)*64+w ----
__global__ __launch_bounds__(256) void transpose_in(const float* __restrict__ x,
                                                    u16* __restrict__ xp) {
    __shared__ float tile[64][65];
    int bid = blockIdx.x;
    int ct = bid & 3, h = (bid >> 2) & 63, b = bid >> 8;
    int t = threadIdx.x;
    int tr = t >> 4, tc = t & 15;
    const float* src = x + (((size_t)(b * 256 + ct * 64) * 64 + h) * 64);
#pragma unroll
    for (int i = 0; i < 4; ++i) {
        int c = tr + i * 16;
        float4 v = *(const float4*)(src + (size_t)c * 4096 + tc * 4);
        tile[c][tc * 4 + 0] = v.x;
        tile[c][tc * 4 + 1] = v.y;
        tile[c][tc * 4 + 2] = v.z;
        tile[c][tc * 4 + 3] = v.w;
    }
    __syncthreads();
    u16* dst = xp + ((size_t)((b * 64 + h) * 64)) * 256 + ct * 64;
#pragma unroll
    for (int i = 0; i < 4; ++i) {
        int w = tr + i * 16;
        ushort4 o;
        o.x = f2bf(tile[tc * 4 + 0][w]);
        o.y = f2bf(tile[tc * 4 + 1][w]);
        o.z = f2bf(tile[tc * 4 + 2][w]);
        o.w = f2bf(tile[tc * 4 + 3][w]);
        *(ushort4*)(dst + (size_t)w * 256 + tc * 4) = o;
    }
}

// ---------------- weight prep: split q row / kv rows, cast bf16 --------------
__global__ __launch_bounds__(256) void prep_w(const float* __restrict__ qw,
                                              const float* __restrict__ qb,
                                              const float* __restrict__ fw,
                                              const float* __restrict__ fb,
                                              float* __restrict__ wq0,
                                              u16* __restrict__ wkv,
                                              float* __restrict__ bkv,
                                              u16* __restrict__ wf,
                                              float* __restrict__ bff) {
    int i = blockIdx.x * 256 + threadIdx.x;  // grid covers 513*256
    if (i < 513 * 256) {
        int o = i >> 8, c = i & 255;
        float v = qw[i];
        if (o == 0) wq0[c] = v;
        else        wkv[(size_t)(o - 1) * 256 + c] = f2bf(v);
    }
    if (i < 65536) wf[i] = f2bf(fw[i]);
    if (i < 512)   bkv[i] = qb[i + 1];
    if (i < 256)   bff[i] = fb[i];
}

// ---------------- K2: per-line softmax(query) + context = sum(key*s) ---------
__global__ __launch_bounds__(256) void softmax_ctx(const float* __restrict__ qbuf,
                                                   const u16* __restrict__ key,
                                                   float* __restrict__ ctx,
                                                   int axis) {
    __shared__ float sc[64];
    int l = blockIdx.x, t = threadIdx.x;
    auto pj = [&](int j) {
        return axis ? ((l >> 6) * 4096 + j * 64 + (l & 63)) : (l * 64 + j);
    };
    if (t < 64) {
        float q = qbuf[pj(t)];
        float m = q;
#pragma unroll
        for (int off = 32; off > 0; off >>= 1) m = fmaxf(m, __shfl_xor(m, off));
        float e = __expf(q - m);
        float s = e;
#pragma unroll
        for (int off = 32; off > 0; off >>= 1) s += __shfl_xor(s, off);
        sc[t] = e / s;
    }
    __syncthreads();
    float acc = 0.f;
#pragma unroll 4
    for (int j = 0; j < 64; ++j) acc += bf2f(key[(size_t)pj(j) * 256 + t]) * sc[j];
    ctx[(size_t)l * 256 + t] = acc;
}

// ---------------- GEMM: MODE 0 = qkv (out key/val/q), 1 = fus->bf16, 2 = fus->fp32 out
template <int MODE>
__global__ __launch_bounds__(256, 2) void gemm_k(
    const u16* __restrict__ Ain, const u16* __restrict__ Bw,
    const float* __restrict__ bias,
    u16* __restrict__ keyOut, u16* __restrict__ valOut,
    float* __restrict__ qOut, const float* __restrict__ wq0,
    const u16* __restrict__ Vin, const float* __restrict__ Ctx, int axis,
    u16* __restrict__ bOut, float* __restrict__ fOut) {
    __shared__ u16 Asm[128][72];
    __shared__ u16 Bsm[128][72];
    int bid = blockIdx.x;
    int otile = (MODE == 0) ? (bid & 3) : (bid & 1);
    int ptile = (MODE == 0) ? (bid >> 2) : (bid >> 1);
    int p0 = ptile * 128, o0 = otile * 128;
    int t = threadIdx.x, lane = t & 63, wv = t >> 6;
    int wm = (wv >> 1) * 64, wn = (wv & 1) * 64;
    f32x4 zero = {0.f, 0.f, 0.f, 0.f};
    f32x4 acc[4][4];
#pragma unroll
    for (int i = 0; i < 4; ++i)
#pragma unroll
        for (int j = 0; j < 4; ++j) acc[i][j] = zero;
    float qacc = 0.f;
    int srow = t >> 3, sch = t & 7;

    for (int k0 = 0; k0 < 256; k0 += 64) {
        __syncthreads();
        // stage B tile: Bsm[o][k]
#pragma unroll
        for (int it = 0; it < 4; ++it) {
            int row = srow + it * 32;
            uint4 v = *(const uint4*)(Bw + (size_t)(o0 + row) * 256 + k0 + sch * 8);
            *(uint4*)&Bsm[row][sch * 8] = v;
        }
        // stage A tile: Asm[p][k]
#pragma unroll
        for (int it = 0; it < 4; ++it) {
            int row = srow + it * 32;
            int rp = p0 + row;
            const u16* ap = Ain + (size_t)rp * 256 + k0 + sch * 8;
            uint4 xv = *(const uint4*)ap;
            if (MODE == 0) {
                *(uint4*)&Asm[row][sch * 8] = xv;
            } else {
                int l = axis ? ((rp >> 12) * 64 + (rp & 63)) : (rp >> 6);
                uint4 vv = *(const uint4*)(Vin + (size_t)rp * 256 + k0 + sch * 8);
                const float* cp = Ctx + (size_t)l * 256 + k0 + sch * 8;
                float4 c0 = *(const float4*)cp;
                float4 c1 = *(const float4*)(cp + 4);
                u16 xs[8], vs[8], ts[8];
                *(uint4*)xs = xv;
                *(uint4*)vs = vv;
                float cf[8] = {c0.x, c0.y, c0.z, c0.w, c1.x, c1.y, c1.z, c1.w};
#pragma unroll
                for (int j = 0; j < 8; ++j)
                    ts[j] = f2bf(bf2f(xs[j]) + sigm(bf2f(vs[j])) * cf[j]);
                *(uint4*)&Asm[row][sch * 8] = *(uint4*)ts;
            }
        }
        __syncthreads();
#pragma unroll
        for (int kk = 0; kk < 64; kk += 32) {
            int kb = kk + (lane >> 4) * 8;
            bf16x8 af[4], bfv[4];
#pragma unroll
            for (int mi = 0; mi < 4; ++mi)
                af[mi] = *(const bf16x8*)&Asm[wm + mi * 16 + (lane & 15)][kb];
#pragma unroll
            for (int ni = 0; ni < 4; ++ni)
                bfv[ni] = *(const bf16x8*)&Bsm[wn + ni * 16 + (lane & 15)][kb];
#pragma unroll
            for (int mi = 0; mi < 4; ++mi)
#pragma unroll
                for (int ni = 0; ni < 4; ++ni)
                    acc[mi][ni] = __builtin_amdgcn_mfma_f32_16x16x32_bf16(
                        af[mi], bfv[ni], acc[mi][ni], 0, 0, 0);
        }
        // query epilogue (uses Asm of this k0; safe before next barrier)
        if (MODE == 0 && otile == 0 && t < 128) {
#pragma unroll
            for (int k = 0; k < 64; k += 8) {
#pragma unroll
                for (int j = 0; j < 8; ++j)
                    qacc += bf2f(Asm[t][k + j]) * wq0[k0 + k + j];
            }
        }
    }
    // store
#pragma unroll
    for (int mi = 0; mi < 4; ++mi) {
#pragma unroll
        for (int ni = 0; ni < 4; ++ni) {
            int col = o0 + wn + ni * 16 + (lane & 15);
            float bv = bias[col];
#pragma unroll
            for (int r = 0; r < 4; ++r) {
                int row = p0 + wm + mi * 16 + ((lane >> 4) << 2) + r;
                float v = acc[mi][ni][r] + bv;
                if (MODE == 0) {
                    if (col < 256) keyOut[(size_t)row * 256 + col] = f2bf(v);
                    else           valOut[(size_t)row * 256 + (col - 256)] = f2bf(v);
                } else if (MODE == 1) {
                    bOut[(size_t)row * 256 + col] = f2bf(v);
                } else {
                    int b = row >> 12;
                    fOut[((size_t)(b * 256 + col)) * 4096 + (row & 4095)] = v;
                }
            }
        }
    }
    if (MODE == 0 && otile == 0 && t < 128) qOut[p0 + t] = qacc;
}

// ---------------- host ----------------
extern "C" void kernel_launch(void* const* d_in, const int* in_sizes, int n_in,
                              void* d_out, int out_size, void* d_ws, size_t ws_size,
                              hipStream_t stream) {
    const float* x   = (const float*)d_in[0];
    const float* qWw = (const float*)d_in[1];
    const float* qWb = (const float*)d_in[2];
    const float* qHw = (const float*)d_in[3];
    const float* qHb = (const float*)d_in[4];
    const float* fWw = (const float*)d_in[5];
    const float* fWb = (const float*)d_in[6];
    const float* fHw = (const float*)d_in[7];
    const float* fHb = (const float*)d_in[8];
    float* out = (float*)d_out;

    char* ws = (char*)d_ws;
    size_t off = 0;
    auto carve = [&](size_t bytes) -> void* {
        off = (off + 255) & ~(size_t)255;
        void* p = ws + off;
        off += bytes;
        return p;
    };
    const size_t P = 65536;
    u16*   xp  = (u16*)carve(P * 256 * 2);     // x' / stage2 key
    u16*   kb  = (u16*)carve(P * 256 * 2);     // stage1 key / x_w'
    u16*   vb  = (u16*)carve(P * 256 * 2);     // value
    float* q   = (float*)carve(P * 4);
    float* cx  = (float*)carve(1024 * 256 * 4);
    float* wq01 = (float*)carve(256 * 4);
    u16*   wkv1 = (u16*)carve(512 * 256 * 2);
    float* bkv1 = (float*)carve(512 * 4);
    u16*   wf1  = (u16*)carve(65536 * 2);
    float* bf1  = (float*)carve(256 * 4);
    float* wq02 = (float*)carve(256 * 4);
    u16*   wkv2 = (u16*)carve(512 * 256 * 2);
    float* bkv2 = (float*)carve(512 * 4);
    u16*   wf2  = (u16*)carve(65536 * 2);
    float* bf2  = (float*)carve(256 * 4);

    prep_w<<<513, 256, 0, stream>>>(qWw, qWb, fWw, fWb, wq01, wkv1, bkv1, wf1, bf1);
    prep_w<<<513, 256, 0, stream>>>(qHw, qHb, fHw, fHb, wq02, wkv2, bkv2, wf2, bf2);
    transpose_in<<<4096, 256, 0, stream>>>(x, xp);

    // ---- stage 1 (axis = W) ----
    gemm_k<0><<<2048, 256, 0, stream>>>(xp, wkv1, bkv1, kb, vb, q, wq01,
                                        nullptr, nullptr, 0, nullptr, nullptr);
    softmax_ctx<<<1024, 256, 0, stream>>>(q, kb, cx, 0);
    gemm_k<1><<<1024, 256, 0, stream>>>(xp, wf1, bf1, nullptr, nullptr, nullptr, nullptr,
                                        vb, cx, 0, kb, nullptr);
    // ---- stage 2 (axis = H), input = kb (x_w') ----
    gemm_k<0><<<2048, 256, 0, stream>>>(kb, wkv2, bkv2, xp, vb, q, wq02,
                                        nullptr, nullptr, 0, nullptr, nullptr);
    softmax_ctx<<<1024, 256, 0, stream>>>(q, xp, cx, 1);
    gemm_k<2><<<1024, 256, 0, stream>>>(kb, wf2, bf2, nullptr, nullptr, nullptr, nullptr,
                                        vb, cx, 1, nullptr, out);
    (void)in_sizes; (void)n_in; (void)out_size; (void)ws_size;
}